// Round 1
// baseline (79719.794 us; speedup 1.0000x reference)
//
#include <hip/hip_runtime.h>
#include <cstdint>
#include <cstddef>

// ---------------------------------------------------------------------------
// Tacotron2-style decoder, fp32, 4 launches per step + one-time precompute.
// Dropout reproduces JAX threefry2x32 (partitionable mode, JAX >= 0.5 default).
// ---------------------------------------------------------------------------

#define JAX_THREEFRY_PARTITIONABLE 1

#define BB   32
#define SS   512
#define EMBD 256
#define MELD 80
#define PRED 256
#define RNND 1024
#define ATTD 128
#define TT   400

// ------------------------------- threefry ---------------------------------
__device__ __forceinline__ void tf_block(uint32_t k0, uint32_t k1,
                                         uint32_t x0, uint32_t x1,
                                         uint32_t& o0, uint32_t& o1) {
  uint32_t ks2 = k0 ^ k1 ^ 0x1BD11BDAu;
  x0 += k0; x1 += k1;
#define TFR(r) { x0 += x1; x1 = (x1 << (r)) | (x1 >> (32 - (r))); x1 ^= x0; }
  TFR(13) TFR(15) TFR(26) TFR(6)
  x0 += k1;  x1 += ks2 + 1u;
  TFR(17) TFR(29) TFR(16) TFR(24)
  x0 += ks2; x1 += k0 + 2u;
  TFR(13) TFR(15) TFR(26) TFR(6)
  x0 += k0;  x1 += k1 + 3u;
  TFR(17) TFR(29) TFR(16) TFR(24)
  x0 += k1;  x1 += ks2 + 4u;
  TFR(13) TFR(15) TFR(26) TFR(6)
  x0 += ks2; x1 += k0 + 5u;
#undef TFR
  o0 = x0; o1 = x1;
}

// subkey j of split(fold_in(key(42), t), 4)
__device__ __forceinline__ void subkey(int t, int j, uint32_t& k0, uint32_t& k1) {
  uint32_t a, b;
  tf_block(0u, 42u, 0u, (uint32_t)t, a, b);   // fold_in (mode-independent)
#if JAX_THREEFRY_PARTITIONABLE
  tf_block(a, b, 0u, (uint32_t)j, k0, k1);    // fold-like split
#else
  // original split: counts [0..7], halves (0..3),(4..7)
  uint32_t base = (uint32_t)((j & 1) * 2);
  uint32_t w = (uint32_t)(j >> 1);
  uint32_t p0, p1, q0, q1;
  tf_block(a, b, base,     base + 4u, p0, p1);
  tf_block(a, b, base + 1u, base + 5u, q0, q1);
  k0 = w ? p1 : p0;
  k1 = w ? q1 : q0;
#endif
}

// bernoulli keep draw for flat index idx of a mask of size n (row-major)
__device__ __forceinline__ bool keep_draw(uint32_t k0, uint32_t k1,
                                          uint32_t idx, uint32_t n, float pkeep) {
  uint32_t bits;
#if JAX_THREEFRY_PARTITIONABLE
  uint32_t o0, o1;
  tf_block(k0, k1, 0u, idx, o0, o1);
  bits = o0 ^ o1;
#else
  uint32_t half = n >> 1;
  uint32_t o0, o1;
  if (idx < half) { tf_block(k0, k1, idx, idx + half, o0, o1); bits = o0; }
  else            { tf_block(k0, k1, idx - half, idx, o0, o1); bits = o1; }
#endif
  float u = __uint_as_float((bits >> 9) | 0x3f800000u) - 1.0f;
  return u < pkeep;
}

__device__ __forceinline__ float sigm(float x) { return 1.0f / (1.0f + expf(-x)); }

// ------------------------------ zero init ---------------------------------
__global__ void zero_kernel(float* p, int n) {
  int i = blockIdx.x * blockDim.x + threadIdx.x;
  if (i < n) p[i] = 0.0f;
}

// --------------------------- prenet (all t) -------------------------------
__global__ __launch_bounds__(256) void prenet_kernel(
    const float* __restrict__ tmels, const float* __restrict__ W1,
    const float* __restrict__ b1, const float* __restrict__ W2,
    const float* __restrict__ b2, float* __restrict__ P_all) {
  __shared__ float melsh[MELD];
  __shared__ float h1sh[PRED];
  int blk = blockIdx.x, tid = threadIdx.x;
  int t = blk >> 5, b = blk & 31;
  if (tid < MELD)
    melsh[tid] = (t == 0) ? 0.0f : tmels[((size_t)b * TT + (t - 1)) * MELD + tid];
  __syncthreads();
  uint32_t k10, k11, k20, k21;
  subkey(t, 0, k10, k11);
  subkey(t, 1, k20, k21);
  {
    const float* wr = W1 + (size_t)tid * MELD;
    float acc = b1[tid];
    for (int m = 0; m < MELD; ++m) acc += melsh[m] * wr[m];
    acc = fmaxf(acc, 0.0f);
    bool kp = keep_draw(k10, k11, (uint32_t)(b * PRED + tid), BB * PRED, 0.5f);
    h1sh[tid] = kp ? (acc / 0.5f) : 0.0f;
  }
  __syncthreads();
  {
    const float* wr = W2 + (size_t)tid * PRED;
    float acc = b2[tid];
    for (int k = 0; k < PRED; ++k) acc += h1sh[k] * wr[k];
    acc = fmaxf(acc, 0.0f);
    bool kp = keep_draw(k20, k21, (uint32_t)(b * PRED + tid), BB * PRED, 0.5f);
    P_all[((size_t)t * BB + b) * PRED + tid] = kp ? (acc / 0.5f) : 0.0f;
  }
}

// ------------------------------ mem_proj ----------------------------------
__global__ __launch_bounds__(128) void memproj_kernel(
    const float* __restrict__ emb, const float* __restrict__ Wmem,
    float* __restrict__ mp) {
  __shared__ float esh[EMBD];
  int blk = blockIdx.x, tid = threadIdx.x;   // blk = b*S + s
  const float* er = emb + (size_t)blk * EMBD;
  esh[tid] = er[tid];
  esh[tid + 128] = er[tid + 128];
  __syncthreads();
  const float4* wr = (const float4*)(Wmem + (size_t)tid * EMBD);
  const float4* xr = (const float4*)esh;
  float acc = 0.0f;
  for (int k4 = 0; k4 < EMBD / 4; ++k4) {
    float4 w = wr[k4], x = xr[k4];
    acc += w.x * x.x + w.y * x.y + w.z * x.z + w.w * x.w;
  }
  mp[(size_t)blk * ATTD + tid] = acc;
}

// --------------------- combo: lstm1(t) + lstm2(t-1) ------------------------
// blocks 0..127: lstm1(t)   K = 256(prenet)+256(ctx)+1024(A_pre) = 1536
// blocks 128..255: lstm2(t-1) K = 1024(B_pre)+256(ctx)+1024(A_post) = 2304
__global__ __launch_bounds__(256) void combo_kernel(
    int t, int do1, int do2,
    const float* __restrict__ P_all,
    const float* __restrict__ ctx_r,
    const float* __restrict__ Apre_r, const float* __restrict__ Bpre_r,
    float* __restrict__ Apre_w, float* __restrict__ Bpre_w,
    const float* __restrict__ Wih_pre, const float* __restrict__ Whh_pre,
    const float* __restrict__ bih_pre, const float* __restrict__ bhh_pre,
    const float* __restrict__ Apost_r, const float* __restrict__ Bpost_r,
    float* __restrict__ Apost_w, float* __restrict__ Bpost_w,
    const float* __restrict__ Wih_post, const float* __restrict__ Whh_post,
    const float* __restrict__ bih_post, const float* __restrict__ bhh_post) {
  __shared__ float xs[BB][256];
  const int blk = blockIdx.x;
  const int tid = threadIdx.x;
  const bool is1 = (blk < 128);
  if (is1 ? !do1 : !do2) return;
  const int tstep = is1 ? t : (t - 1);
  const int hb = (is1 ? blk : blk - 128) * 8;
  const int col = tid & 31;
  const int lq  = tid >> 5;        // 0..7
  const int b0  = lq * 4;
  const int gate = col >> 3;       // 0..3 (i,f,g,o)
  const int hl   = col & 7;
  const int gcol = gate * RNND + hb + hl;
  const int nchunks = is1 ? 6 : 9;

  float acc0 = 0.f, acc1 = 0.f, acc2 = 0.f, acc3 = 0.f;

  for (int ch = 0; ch < nchunks; ++ch) {
    __syncthreads();
#pragma unroll
    for (int it = 0; it < 8; ++it) {
      int flat = tid + it * 256;       // 0..2047 float4 slots (32 b x 64 f4)
      int bb = flat >> 6;
      int k4 = flat & 63;
      const float* src;
      if (is1) {
        if (ch == 0)      src = P_all + ((size_t)t * BB + bb) * PRED;
        else if (ch == 1) src = ctx_r + (size_t)bb * EMBD;
        else              src = Apre_r + (size_t)bb * RNND + (ch - 2) * 256;
      } else {
        if (ch < 4)       src = Bpre_r + (size_t)bb * RNND + ch * 256;
        else if (ch == 4) src = ctx_r + (size_t)bb * EMBD;
        else              src = Apost_r + (size_t)bb * RNND + (ch - 5) * 256;
      }
      float4 v4 = *(((const float4*)src) + k4);
      *(((float4*)&xs[bb][0]) + k4) = v4;
    }
    __syncthreads();

    const float* wrow;
    if (is1) wrow = (ch < 2) ? (Wih_pre + (size_t)gcol * 512 + ch * 256)
                             : (Whh_pre + (size_t)gcol * 1024 + (ch - 2) * 256);
    else     wrow = (ch < 5) ? (Wih_post + (size_t)gcol * 1280 + ch * 256)
                             : (Whh_post + (size_t)gcol * 1024 + (ch - 5) * 256);
    const float4* w4p = (const float4*)wrow;
#pragma unroll 8
    for (int k4 = 0; k4 < 64; ++k4) {
      float4 w = w4p[k4];
      float4 xa = *(((const float4*)&xs[b0 + 0][0]) + k4);
      float4 xb = *(((const float4*)&xs[b0 + 1][0]) + k4);
      float4 xc = *(((const float4*)&xs[b0 + 2][0]) + k4);
      float4 xd = *(((const float4*)&xs[b0 + 3][0]) + k4);
      acc0 += w.x * xa.x + w.y * xa.y + w.z * xa.z + w.w * xa.w;
      acc1 += w.x * xb.x + w.y * xb.y + w.z * xb.z + w.w * xb.w;
      acc2 += w.x * xc.x + w.y * xc.y + w.z * xc.z + w.w * xc.w;
      acc3 += w.x * xd.x + w.y * xd.y + w.z * xd.z + w.w * xd.w;
    }
  }

  float bsum = is1 ? (bih_pre[gcol] + bhh_pre[gcol])
                   : (bih_post[gcol] + bhh_post[gcol]);
  acc0 += bsum; acc1 += bsum; acc2 += bsum; acc3 += bsum;

  // gather f,g,o into gate==0 lanes (same 32-lane half: +8,+16,+24)
  int lane = tid & 63;
  float f0 = __shfl(acc0, lane + 8),  f1 = __shfl(acc1, lane + 8);
  float f2 = __shfl(acc2, lane + 8),  f3 = __shfl(acc3, lane + 8);
  float g0 = __shfl(acc0, lane + 16), g1 = __shfl(acc1, lane + 16);
  float g2 = __shfl(acc2, lane + 16), g3 = __shfl(acc3, lane + 16);
  float q0 = __shfl(acc0, lane + 24), q1 = __shfl(acc1, lane + 24);
  float q2 = __shfl(acc2, lane + 24), q3 = __shfl(acc3, lane + 24);

  if (gate == 0) {
    uint32_t kk0, kk1;
    subkey(tstep, is1 ? 2 : 3, kk0, kk1);
    const int h = hb + hl;
    const float* Bold = is1 ? Bpre_r : Bpost_r;
    float* Aw = is1 ? Apre_w : Apost_w;
    float* Bw = is1 ? Bpre_w : Bpost_w;
    float ia[4] = {acc0, acc1, acc2, acc3};
    float fa[4] = {f0, f1, f2, f3};
    float ga[4] = {g0, g1, g2, g3};
    float oa[4] = {q0, q1, q2, q3};
#pragma unroll
    for (int i2 = 0; i2 < 4; ++i2) {
      int bb = b0 + i2;
      float iv = sigm(ia[i2]);
      float fv = sigm(fa[i2]);
      float gv = tanhf(ga[i2]);
      float ov = sigm(oa[i2]);
      float c_new = fv * Bold[(size_t)bb * RNND + h] + iv * gv;
      float h_new = ov * tanhf(c_new);
      bool kp = keep_draw(kk0, kk1, (uint32_t)(bb * RNND + h), BB * RNND, 0.9f);
      Aw[(size_t)bb * RNND + h] = kp ? (h_new / 0.9f) : 0.0f;
      Bw[(size_t)bb * RNND + h] = c_new;
    }
  }
}

// ------------------------------ q = h_pre @ Wq^T ---------------------------
__global__ __launch_bounds__(256) void q_kernel(
    const float* __restrict__ Bpre_new, const float* __restrict__ Wq,
    float* __restrict__ qout) {
  __shared__ float xsh[2][RNND];
  int blk = blockIdx.x, tid = threadIdx.x;
  int b2 = blk * 2;
  for (int flat = tid; flat < 2 * RNND; flat += 256)
    xsh[flat >> 10][flat & 1023] =
        Bpre_new[(size_t)(b2 + (flat >> 10)) * RNND + (flat & 1023)];
  __syncthreads();
  int a = tid & 127, bh = tid >> 7;
  const float4* wr = (const float4*)(Wq + (size_t)a * RNND);
  const float4* xr = (const float4*)&xsh[bh][0];
  float acc = 0.0f;
  for (int k4 = 0; k4 < RNND / 4; ++k4) {
    float4 w = wr[k4], x = xr[k4];
    acc += w.x * x.x + w.y * x.y + w.z * x.z + w.w * x.w;
  }
  qout[(size_t)(b2 + bh) * ATTD + a] = acc;
}

// -------- energies (blocks 0..255) + output projection t-1 (256..287) ------
__global__ __launch_bounds__(256) void att_kernel(
    int do_att, int do_out, int t_prev,
    const float* __restrict__ qin, const float* __restrict__ memproj,
    const float* __restrict__ aw_r, const float* __restrict__ asum_r,
    const float* __restrict__ conv_w, const float* __restrict__ Wloc,
    const float* __restrict__ vvec, float* __restrict__ energ,
    const float* __restrict__ Bpost_o, const float* __restrict__ ctx_o,
    const float* __restrict__ Wmel, const float* __restrict__ bmel,
    const float* __restrict__ Wstop, const float* __restrict__ bstop,
    float* __restrict__ dout) {
  int blk = blockIdx.x, tid = threadIdx.x;
  if (blk >= 256) {
    if (!do_out) return;
    int b = blk - 256;
    int o = tid;
    if (o > 80) return;
    const float* wrow = (o < 80) ? (Wmel + (size_t)o * 1280) : Wstop;
    const float4* w4 = (const float4*)wrow;
    const float4* x4 = (const float4*)(Bpost_o + (size_t)b * RNND);
    float acc = 0.0f;
    for (int k4 = 0; k4 < RNND / 4; ++k4) {
      float4 w = w4[k4], x = x4[k4];
      acc += w.x * x.x + w.y * x.y + w.z * x.z + w.w * x.w;
    }
    const float4* w4b = (const float4*)(wrow + RNND);
    const float4* c4 = (const float4*)(ctx_o + (size_t)b * EMBD);
    for (int k4 = 0; k4 < EMBD / 4; ++k4) {
      float4 w = w4b[k4], x = c4[k4];
      acc += w.x * x.x + w.y * x.y + w.z * x.z + w.w * x.w;
    }
    acc += (o < 80) ? bmel[o] : bstop[0];
    float val = sigm(acc);
    if (o < 80) dout[(size_t)b * (TT * MELD) + (size_t)t_prev * MELD + o] = val;
    else        dout[(size_t)BB * TT * MELD + (size_t)b * TT + t_prev] = val;
    return;
  }
  if (!do_att) return;
  __shared__ float qsh[ATTD];
  __shared__ float vsh[ATTD];
  __shared__ float awin[94], aswin[94];
  __shared__ float wlocs[ATTD * 33];
  __shared__ float convs[32 * 62];
  __shared__ float locs[64 * 33];
  int b = blk >> 3, st = blk & 7, s0 = st * 64;
  if (tid < ATTD) { qsh[tid] = qin[b * ATTD + tid]; vsh[tid] = vvec[tid]; }
  if (tid < 94) {
    int sg = s0 - 15 + tid;
    bool ok = (sg >= 0) && (sg < SS);
    awin[tid]  = ok ? aw_r[b * SS + sg]   : 0.0f;
    aswin[tid] = ok ? asum_r[b * SS + sg] : 0.0f;
  }
  for (int idx = tid; idx < ATTD * 32; idx += 256) {
    int a = idx >> 5, c = idx & 31;
    wlocs[a * 33 + c] = Wloc[a * 32 + c];
  }
  for (int idx = tid; idx < 32 * 62; idx += 256) convs[idx] = conv_w[idx];
  __syncthreads();
  // conv: loc[s][c], channel0 = a_sum, channel1 = a_w, kernel 31, pad 15
  for (int idx = tid; idx < 64 * 32; idx += 256) {
    int sl = idx & 63, c = idx >> 6;
    const float* cw0 = &convs[c * 62];
    const float* cw1 = &convs[c * 62 + 31];
    float acc = 0.0f;
    for (int k = 0; k < 31; ++k)
      acc += cw0[k] * aswin[sl + k] + cw1[k] * awin[sl + k];
    locs[sl * 33 + c] = acc;
  }
  __syncthreads();
  int sl = tid >> 2, aq = tid & 3, sg = s0 + sl;
  const float* mp = memproj + ((size_t)b * SS + sg) * ATTD;
  float acc = 0.0f;
  const float* ls = &locs[sl * 33];
  for (int j = 0; j < 32; ++j) {
    int a = j * 4 + aq;
    const float* wl = &wlocs[a * 33];
    float lp = 0.0f;
#pragma unroll 8
    for (int c = 0; c < 32; ++c) lp += ls[c] * wl[c];
    acc += vsh[a] * tanhf(qsh[a] + mp[a] + lp);
  }
  acc += __shfl_down(acc, 2);
  acc += __shfl_down(acc, 1);
  if (aq == 0) energ[b * SS + sg] = acc;
}

// ---------------- softmax + context + a_w/a_sum update ---------------------
__global__ __launch_bounds__(256) void sm_ctx_kernel(
    const float* __restrict__ energ, const float* __restrict__ emb,
    const float* __restrict__ asum_r, float* __restrict__ aw_w,
    float* __restrict__ asum_w, float* __restrict__ ctx_w) {
  __shared__ float psh[SS];
  __shared__ float red[256];
  __shared__ float cpart[4][64];
  int blk = blockIdx.x, tid = threadIdx.x;
  int b = blk >> 2, ec = blk & 3;
  float e1 = energ[b * SS + tid], e2 = energ[b * SS + 256 + tid];
  red[tid] = fmaxf(e1, e2);
  __syncthreads();
  for (int s = 128; s > 0; s >>= 1) {
    if (tid < s) red[tid] = fmaxf(red[tid], red[tid + s]);
    __syncthreads();
  }
  float mx = red[0];
  __syncthreads();
  float p1 = expf(e1 - mx), p2 = expf(e2 - mx);
  psh[tid] = p1; psh[tid + 256] = p2;
  red[tid] = p1 + p2;
  __syncthreads();
  for (int s = 128; s > 0; s >>= 1) {
    if (tid < s) red[tid] += red[tid + s];
    __syncthreads();
  }
  float inv = 1.0f / red[0];
  int el = tid & 63, sq = tid >> 6;
  int e = ec * 64 + el;
  float acc = 0.0f;
  const float* ebase = emb + ((size_t)b * SS) * EMBD + e;
  for (int s = sq * 128; s < sq * 128 + 128; ++s)
    acc += psh[s] * ebase[(size_t)s * EMBD];
  cpart[sq][el] = acc;
  __syncthreads();
  if (tid < 64)
    ctx_w[b * EMBD + ec * 64 + tid] =
        (cpart[0][tid] + cpart[1][tid] + cpart[2][tid] + cpart[3][tid]) * inv;
  if (ec == 0) {
    float a1 = p1 * inv, a2 = p2 * inv;
    aw_w[b * SS + tid] = a1;
    aw_w[b * SS + 256 + tid] = a2;
    asum_w[b * SS + tid] = asum_r[b * SS + tid] + a1;
    asum_w[b * SS + 256 + tid] = asum_r[b * SS + 256 + tid] + a2;
  }
}

// ------------------------------- launch ------------------------------------
extern "C" void kernel_launch(void* const* d_in, const int* in_sizes, int n_in,
                              void* d_out, int out_size, void* d_ws, size_t ws_size,
                              hipStream_t stream) {
  const float* emb      = (const float*)d_in[0];
  const float* tmels    = (const float*)d_in[1];
  const float* W1       = (const float*)d_in[2];
  const float* b1       = (const float*)d_in[3];
  const float* W2       = (const float*)d_in[4];
  const float* b2       = (const float*)d_in[5];
  const float* Wih_pre  = (const float*)d_in[6];
  const float* Whh_pre  = (const float*)d_in[7];
  const float* bih_pre  = (const float*)d_in[8];
  const float* bhh_pre  = (const float*)d_in[9];
  const float* Wq       = (const float*)d_in[10];
  const float* Wmem     = (const float*)d_in[11];
  const float* conv_w   = (const float*)d_in[12];
  const float* Wloc     = (const float*)d_in[13];
  const float* vvec     = (const float*)d_in[14];
  const float* Wih_post = (const float*)d_in[15];
  const float* Whh_post = (const float*)d_in[16];
  const float* bih_post = (const float*)d_in[17];
  const float* bhh_post = (const float*)d_in[18];
  const float* Wmel     = (const float*)d_in[19];
  const float* bmel     = (const float*)d_in[20];
  const float* Wstop    = (const float*)d_in[21];
  const float* bstop    = (const float*)d_in[22];
  float* out = (float*)d_out;

  float* w = (float*)d_ws;
  size_t off = 0;
  auto carve = [&](size_t n) {
    float* p = w + off;
    off += (n + 63) & ~((size_t)63);
    return p;
  };
  float* memproj = carve((size_t)BB * SS * ATTD);
  float* P_all   = carve((size_t)TT * BB * PRED);
  size_t state_begin = off;
  float* Apre[2]  = {carve(BB * RNND), carve(BB * RNND)};
  float* Bpre[2]  = {carve(BB * RNND), carve(BB * RNND)};
  float* Apost[2] = {carve(BB * RNND), carve(BB * RNND)};
  float* Bpost[2] = {carve(BB * RNND), carve(BB * RNND)};
  float* ctx[2]   = {carve(BB * EMBD), carve(BB * EMBD)};
  float* aw[2]    = {carve(BB * SS), carve(BB * SS)};
  float* asum[2]  = {carve(BB * SS), carve(BB * SS)};
  size_t state_end = off;
  float* q     = carve(BB * ATTD);
  float* energ = carve(BB * SS);

  // zero the recurrent state region (both parities)
  int nz = (int)(state_end - state_begin);
  zero_kernel<<<(nz + 255) / 256, 256, 0, stream>>>(w + state_begin, nz);

  prenet_kernel<<<TT * BB, 256, 0, stream>>>(tmels, W1, b1, W2, b2, P_all);
  memproj_kernel<<<BB * SS, 128, 0, stream>>>(emb, Wmem, memproj);

  for (int t = 0; t <= TT; ++t) {
    int r = t & 1, wr2 = 1 - r;
    combo_kernel<<<256, 256, 0, stream>>>(
        t, (int)(t < TT), (int)(t > 0),
        P_all, ctx[r], Apre[r], Bpre[r], Apre[wr2], Bpre[wr2],
        Wih_pre, Whh_pre, bih_pre, bhh_pre,
        Apost[wr2], Bpost[wr2], Apost[r], Bpost[r],
        Wih_post, Whh_post, bih_post, bhh_post);
    if (t < TT) {
      q_kernel<<<16, 256, 0, stream>>>(Bpre[wr2], Wq, q);
      att_kernel<<<288, 256, 0, stream>>>(
          1, (int)(t > 0), t - 1,
          q, memproj, aw[r], asum[r], conv_w, Wloc, vvec, energ,
          Bpost[r], ctx[r], Wmel, bmel, Wstop, bstop, out);
      sm_ctx_kernel<<<128, 256, 0, stream>>>(
          energ, emb, asum[r], aw[wr2], asum[wr2], ctx[wr2]);
    } else {
      att_kernel<<<288, 256, 0, stream>>>(
          0, 1, t - 1,
          q, memproj, aw[r], asum[r], conv_w, Wloc, vvec, energ,
          Bpost[r], ctx[r], Wmel, bmel, Wstop, bstop, out);
    }
  }
  (void)in_sizes; (void)n_in; (void)out_size; (void)ws_size;
}